// Round 11
// baseline (30.669 us; speedup 1.0000x reference)
//
#include <hip/hip_runtime.h>

// PolyAttn collapse: a = s^4/|s^4| == 1.0 identically, so
//   out[b,n,:] = vsum[b,:] @ w_o  (independent of n, q, k, alpha),
//   vsum[b,:]  = (sum_n x[b,n,:]) @ w_qkv[:, 2H:3H].
// R11: new decomposition. R6/R8/R10 proved kB/kC micro-structure irrelevant
// (all ~29-30us) -> replace the pipeline: fuse colsum+Wv per d-slice (kXV),
// tiny fold (kFold), fuse Wo-slice+broadcast (kOut). No atomics, no zeroing,
// no xsum round-trip. Grid barriers / spin-waits remain banned (R3/R4/R7).

#define B_ 4
#define N_ 2048
#define D_ 1024
#define H_ 1024
#define H3_ 3072

__device__ __forceinline__ void f4add(float4& a, const float4 b) {
    a.x += b.x; a.y += b.y; a.z += b.z; a.w += b.w;
}

// ws layout (floats): vspart[64][4][1024] (1 MB) | vsum[4][1024]

// ---- kXV: 256 blocks (b*64+s). colsum of x[b,:,s*16..+16], then @Wv slice.
__global__ __launch_bounds__(256) void kXV(const float* __restrict__ x,
                                           const float* __restrict__ w_qkv,
                                           float4* __restrict__ vspart4) {
    const int blk = blockIdx.x;
    const int b = blk >> 6, s = blk & 63;
    const int t = threadIdx.x;
    const int c4 = t & 3;                  // float4 col within 16-float slice
    const int rs = t >> 2;                 // 64 row streams
    __shared__ float4 s_acc[256];

    const float4* x4 = reinterpret_cast<const float4*>(x);
    float4 acc = make_float4(0.f, 0.f, 0.f, 0.f);
    size_t base = ((size_t)b * N_ + rs) * (D_ / 4) + s * 4 + c4;
#pragma unroll 16
    for (int i = 0; i < 32; ++i)           // rows rs + 64*i
        f4add(acc, x4[base + (size_t)i * 64 * (D_ / 4)]);
    s_acc[t] = acc;
    __syncthreads();
    // tree-reduce over rs (keep c4): offs 128..4 are multiples of 4
    for (int off = 128; off >= 4; off >>= 1) {
        if (t < off) f4add(s_acc[t], s_acc[t + off]);
        __syncthreads();
    }
    // s_acc[0..3] = cs[16] (colsum of the 16-float slice)
    const float* cs = reinterpret_cast<const float*>(s_acc);
    const float4* wv4 = reinterpret_cast<const float4*>(w_qkv);
    float4 vp = make_float4(0.f, 0.f, 0.f, 0.f);
    size_t wbase = (size_t)(s * 16) * (H3_ / 4) + (2 * H_ / 4) + t;
#pragma unroll
    for (int j = 0; j < 16; ++j) {
        const float c = cs[j];             // LDS broadcast
        const float4 w = wv4[wbase + (size_t)j * (H3_ / 4)];  // 4KB coalesced
        vp.x += c * w.x; vp.y += c * w.y; vp.z += c * w.z; vp.w += c * w.w;
    }
    vspart4[(size_t)(s * 4 + b) * 256 + t] = vp;   // plain store
}

// ---- kFold: 4 blocks x 256: vsum[b][h] = sum_s vspart[s][b][h] ------------
__global__ __launch_bounds__(256) void kFold(const float4* __restrict__ vspart4,
                                             float4* __restrict__ vsum4) {
    const int i = blockIdx.x * 256 + threadIdx.x;  // (b, h4)
    const int b = i >> 8, h4 = i & 255;
    const float4* p = vspart4 + b * 256 + h4;
    float4 acc = make_float4(0.f, 0.f, 0.f, 0.f);
#pragma unroll 16
    for (int s = 0; s < 64; ++s)
        f4add(acc, p[(size_t)s * 1024]);
    vsum4[i] = acc;
}

// ---- kOut: 256 blocks (b*64+sl): orow slice = vsum[b,:]@Wo[:,slice]; bcast.
__global__ __launch_bounds__(256) void kOut(const float4* __restrict__ vsum4,
                                            const float* __restrict__ w_o,
                                            float* __restrict__ out) {
    const int blk = blockIdx.x;
    const int b = blk >> 6, sl = blk & 63;
    const int t = threadIdx.x;
    const int c4 = t & 3;
    __shared__ float4 s_vs[256];           // vsum[b,:] (1024 floats)
    __shared__ float4 s_red[256];

    s_vs[t] = vsum4[b * 256 + t];
    __syncthreads();
    const float* vs = reinterpret_cast<const float*>(s_vs);
    const float4* wo4 = reinterpret_cast<const float4*>(w_o);
    const int hg = t >> 2;                 // 64 h-groups of 16
    float4 acc = make_float4(0.f, 0.f, 0.f, 0.f);
    size_t wbase = (size_t)(hg * 16) * (D_ / 4) + sl * 4 + c4;
#pragma unroll
    for (int j = 0; j < 16; ++j) {
        const float v = vs[hg * 16 + j];
        const float4 w = wo4[wbase + (size_t)j * (D_ / 4)];
        acc.x += v * w.x; acc.y += v * w.y; acc.z += v * w.z; acc.w += v * w.w;
    }
    s_red[t] = acc;
    __syncthreads();
    for (int off = 128; off >= 4; off >>= 1) {
        if (t < off) f4add(s_red[t], s_red[t + off]);
        __syncthreads();
    }
    // s_red[0..3] = orow slice (16 floats); broadcast to all 2048 rows
    const float4 os = s_red[c4];
    float4* out4 = reinterpret_cast<float4*>(out);
    const int rs = t >> 2;                 // 64 row streams x 32 rows
    size_t obase = ((size_t)b * N_ + rs) * (D_ / 4) + sl * 4 + c4;
#pragma unroll 16
    for (int i = 0; i < 32; ++i)
        out4[obase + (size_t)i * 64 * (D_ / 4)] = os;
}

extern "C" void kernel_launch(void* const* d_in, const int* in_sizes, int n_in,
                              void* d_out, int out_size, void* d_ws, size_t ws_size,
                              hipStream_t stream) {
    const float* x     = (const float*)d_in[0];   // [B, N, D]
    const float* w_qkv = (const float*)d_in[1];   // [D, 3H]
    const float* w_o   = (const float*)d_in[2];   // [H, D]
    // d_in[3] = alpha — provably unused (a == 1 regardless of alpha).
    float* out = (float*)d_out;                   // [B, N, D] fp32

    float* vspart = (float*)d_ws;                 // 64*4*1024 = 262144 floats
    float* vsum   = vspart + 64 * B_ * H_;        // 4096 floats

    kXV<<<256, 256, 0, stream>>>(x, w_qkv, (float4*)vspart);
    kFold<<<4, 256, 0, stream>>>((const float4*)vspart, (float4*)vsum);
    kOut<<<256, 256, 0, stream>>>((const float4*)vsum, w_o, out);
}